// Round 1
// baseline (607.993 us; speedup 1.0000x reference)
//
#include <hip/hip_runtime.h>

// Direct 3x3 valid cross-correlation + bias, fp32.
// x: [32,64,64,64], w: [64,64,3,3], b: [64], out: [32,64,62,62]
// Block = 256 threads = 4 waves, handles one (n, oh) pair: all 64 f, all 62 ow.
//   ow  = tid & 63   (lanes 62,63 compute garbage, store is guarded)
//   sub = tid >> 6   (wave id, uniform per wave) -> f0 = sub*16
// Wave-uniform w addresses -> scalar loads; x staged per-channel in LDS.

#define N_  32
#define C_  64
#define H_  64
#define W_  64
#define F_  64
#define OH_ 62
#define OW_ 62

__global__ __launch_bounds__(256) void conv3x3_direct(
    const float* __restrict__ x,
    const float* __restrict__ w,
    const float* __restrict__ b,
    float* __restrict__ out)
{
    // 3 rows of 64, padded so reads at col ow+2 for ow=63 stay in-bounds.
    __shared__ float sx[3 * 64 + 16];

    const int n   = blockIdx.x;
    const int oh  = blockIdx.y;
    const int t   = threadIdx.x;
    const int ow  = t & 63;
    const int sub = t >> 6;       // wave-uniform
    const int f0  = sub * 16;     // wave-uniform

    float acc[16];
#pragma unroll
    for (int i = 0; i < 16; ++i) acc[i] = b[f0 + i];

    // base of x[n][0][oh][0]
    const float* xbase = x + ((size_t)n * C_) * (H_ * W_) + (size_t)oh * W_;

    // staging role: threads 0..191 load row r = t>>6, col t&63
    const int st_r   = t >> 6;
    const int st_col = t & 63;

    for (int c = 0; c < C_; ++c) {
        if (t < 192) {
            sx[st_r * 64 + st_col] =
                xbase[(size_t)c * (H_ * W_) + st_r * W_ + st_col];
        }
        __syncthreads();

        // gather the 3x3 window (unguarded; LDS padded)
        float xv[9];
#pragma unroll
        for (int r = 0; r < 3; ++r)
#pragma unroll
            for (int kc = 0; kc < 3; ++kc)
                xv[r * 3 + kc] = sx[r * 64 + ow + kc];

        // 16 filters x 9 taps; w address wave-uniform -> s_load + SGPR FMA
#pragma unroll
        for (int i = 0; i < 16; ++i) {
            const float* wp = w + ((size_t)(f0 + i) * C_ + c) * 9;
#pragma unroll
            for (int tap = 0; tap < 9; ++tap)
                acc[i] += xv[tap] * wp[tap];
        }
        __syncthreads();
    }

    if (ow < OW_) {
#pragma unroll
        for (int i = 0; i < 16; ++i)
            out[(((size_t)n * F_ + (f0 + i)) * OH_ + oh) * OW_ + ow] = acc[i];
    }
}

extern "C" void kernel_launch(void* const* d_in, const int* in_sizes, int n_in,
                              void* d_out, int out_size, void* d_ws, size_t ws_size,
                              hipStream_t stream)
{
    const float* x = (const float*)d_in[0];
    const float* w = (const float*)d_in[1];
    const float* b = (const float*)d_in[2];
    float* out = (float*)d_out;

    dim3 grid(N_, OH_);   // 32 x 62 blocks
    conv3x3_direct<<<grid, 256, 0, stream>>>(x, w, b, out);
}

// Round 2
// 97.957 us; speedup vs baseline: 6.2067x; 6.2067x over previous
//
#include <hip/hip_runtime.h>

// bf16 MFMA implicit GEMM for 3x3 valid conv + bias.
// x: [32,64,64,64] f32, w: [64,64,3,3] f32, b: [64] f32, out: [32,64,62,62] f32
//
// GEMM per tap (r,s), per c-chunk of 16:  D[f][ow] += W[f][c] * X[c][ow]
// MFMA 32x32x16 bf16, A = w (m=f), B = x (n=ow)  ->  C/D col = lane&31 = ow
// (coalesced stores, no transpose epilogue).
// Block = 256 thr = 4 waves = (n, oh0..oh0+3); wave tile 64f x 64ow (2x2 MFMAs).

#define N_  32
#define C_  64
#define H_  64
#define W_  64
#define F_  64
#define OH_ 62
#define OW_ 62

typedef __attribute__((ext_vector_type(8)))  short short8;
typedef __attribute__((ext_vector_type(16))) float float16;

union Frag { unsigned int u[4]; short8 s; };

__device__ __forceinline__ unsigned short f2bf(float v) {
    unsigned int u = __builtin_bit_cast(unsigned int, v);
    u += 0x7FFFu + ((u >> 16) & 1u);
    return (unsigned short)(u >> 16);
}

// w [F][C][3][3] f32  ->  w_t [chunk(4)][tap(9)][f(64)][c16(16)] bf16
__global__ __launch_bounds__(256) void wprep(const float* __restrict__ w,
                                             unsigned short* __restrict__ wt) {
    int tid = blockIdx.x * 256 + threadIdx.x;      // 0..36863
    int c16   = tid & 15;
    int f     = (tid >> 4) & 63;
    int ct    = tid >> 10;                         // chunk*9 + tap
    int tap   = ct % 9;
    int chunk = ct / 9;
    wt[tid] = f2bf(w[(f * 64 + chunk * 16 + c16) * 9 + tap]);
}

__global__ __launch_bounds__(256, 2) void conv_mfma(
    const float* __restrict__ x,
    const unsigned short* __restrict__ wt,
    const float* __restrict__ b,
    float* __restrict__ out)
{
    // x LDS: [row 6][col 66][c16 pad to 18 shorts = 9 dwords]
    __shared__ unsigned int xl[6 * 66 * 9];        // 14256 B
    // w LDS: [tap 9][f 64][c16 pad to 18 shorts = 9 dwords]
    __shared__ unsigned int wl[9 * 64 * 9];        // 20736 B
    unsigned short* xs = (unsigned short*)xl;

    const int n   = blockIdx.x;        // image
    const int oh0 = blockIdx.y * 4;    // first oh row of block
    const int t   = threadIdx.x;
    const int wv  = t >> 6;            // wave id = oh row offset
    const int ln31 = t & 31;
    const int cgrp = (t >> 5) & 1;     // k-half of the wave
    const int col  = t & 63;           // staging column

    const int oh = oh0 + wv;

    float16 acc00 = {0}, acc01 = {0}, acc10 = {0}, acc11 = {0};

    for (int chunk = 0; chunk < 4; ++chunk) {
        const int c0 = chunk * 16;
        __syncthreads();   // protect LDS from previous iteration's readers

        // ---- stage x chunk: 6 rows x 64 cols x 16 c, f32 -> bf16 ----
        // thread covers (r6, c16) pairs: egrp = wv + 4*(i3 + 3*j)... pattern:
        // i3 in 0..2 fixes r6 and c16 parity; j in 0..7 steps c16 by 2.
        {
            float xv[24];
#pragma unroll
            for (int i3 = 0; i3 < 3; ++i3) {
                int eg   = wv + 4 * i3;            // 0..11
                int r6   = (eg < 6) ? eg : eg - 6;
                int c16b = (eg < 6) ? 0 : 1;
                int rowg = oh0 + r6; if (rowg > 63) rowg = 63;
                const float* xr = x + (((n * 64 + c0 + c16b) * 64 + rowg) * 64 + col);
#pragma unroll
                for (int j = 0; j < 8; ++j)
                    xv[i3 * 8 + j] = xr[(size_t)j * 2 * 4096];  // c += 2 per j
            }
#pragma unroll
            for (int i3 = 0; i3 < 3; ++i3) {
                int eg   = wv + 4 * i3;
                int r6   = (eg < 6) ? eg : eg - 6;
                int c16b = (eg < 6) ? 0 : 1;
                int base = (r6 * 66 + col) * 18 + c16b;
#pragma unroll
                for (int j = 0; j < 8; ++j)
                    xs[base + 2 * j] = f2bf(xv[i3 * 8 + j]);
            }
        }

        // ---- stage w chunk: 9 taps x 64 f x 16 c bf16 (already converted) ----
        {
            const uint4* wt4 = (const uint4*)(wt + chunk * 9216);  // 16B chunks
#pragma unroll
            for (int i = 0; i < 5; ++i) {
                int k = t + 256 * i;                // 0..1151 chunks of 8 bf16
                if (k < 1152) {
                    uint4 v = wt4[k];
                    int half = k & 1, f = (k >> 1) & 63, tap = k >> 7;
                    unsigned int* dst = wl + (tap * 64 + f) * 9 + half * 4;
                    dst[0] = v.x; dst[1] = v.y; dst[2] = v.z; dst[3] = v.w;
                }
            }
        }
        __syncthreads();

        // ---- 9 taps x 2x2 MFMA ----
#pragma unroll
        for (int r = 0; r < 3; ++r) {
#pragma unroll
            for (int s = 0; s < 3; ++s) {
                const int tap = r * 3 + s;
                Frag a0, a1, b0, b1;
                const unsigned int* wbase = wl + tap * 64 * 9 + cgrp * 4;
                const unsigned int* xbase = xl + ((wv + r) * 66 + s) * 9 + cgrp * 4;
#pragma unroll
                for (int j = 0; j < 4; ++j) {
                    a0.u[j] = wbase[(ln31)      * 9 + j];
                    a1.u[j] = wbase[(ln31 + 32) * 9 + j];
                    b0.u[j] = xbase[(ln31)      * 9 + j];
                    b1.u[j] = xbase[(ln31 + 32) * 9 + j];
                }
                acc00 = __builtin_amdgcn_mfma_f32_32x32x16_bf16(a0.s, b0.s, acc00, 0, 0, 0);
                acc01 = __builtin_amdgcn_mfma_f32_32x32x16_bf16(a0.s, b1.s, acc01, 0, 0, 0);
                acc10 = __builtin_amdgcn_mfma_f32_32x32x16_bf16(a1.s, b0.s, acc10, 0, 0, 0);
                acc11 = __builtin_amdgcn_mfma_f32_32x32x16_bf16(a1.s, b1.s, acc11, 0, 0, 0);
            }
        }
    }

    // ---- epilogue: direct coalesced stores, bias folded ----
    if (oh < OH_) {
#pragma unroll
        for (int fs = 0; fs < 2; ++fs) {
#pragma unroll
            for (int r = 0; r < 16; ++r) {
                int f = fs * 32 + (r & 3) + 8 * (r >> 2) + 4 * cgrp;
                float bias = b[f];
                float v0 = (fs ? (r < 4 ? acc10[r] : acc10[r]) : acc00[r]);
                float v1 = (fs ? acc11[r] : acc01[r]);
                v0 = (fs ? acc10[r] : acc00[r]);
                float* orow = out + (((size_t)n * 64 + f) * OH_ + oh) * OW_;
                orow[ln31] = v0 + bias;                       // ow = ln31 < 62 always
                if (ln31 < 30) orow[32 + ln31] = v1 + bias;   // ow = 32+ln31
            }
        }
    }
}

extern "C" void kernel_launch(void* const* d_in, const int* in_sizes, int n_in,
                              void* d_out, int out_size, void* d_ws, size_t ws_size,
                              hipStream_t stream)
{
    const float* x = (const float*)d_in[0];
    const float* w = (const float*)d_in[1];
    const float* b = (const float*)d_in[2];
    float* out = (float*)d_out;
    unsigned short* wt = (unsigned short*)d_ws;    // 36864 bf16 = 73728 B

    wprep<<<144, 256, 0, stream>>>(w, wt);
    dim3 grid(N_, 16);                             // 32 images x 16 oh-blocks
    conv_mfma<<<grid, 256, 0, stream>>>(x, wt, b, out);
}

// Round 3
// 95.603 us; speedup vs baseline: 6.3596x; 1.0246x over previous
//
#include <hip/hip_runtime.h>

// bf16 MFMA implicit GEMM for 3x3 valid conv + bias — b128 LDS edition.
// x: [32,64,64,64] f32, w: [64,64,3,3] f32, b: [64] f32, out: [32,64,62,62] f32
//
// Per tap (r,s), per c-chunk of 16:  D[f][ow] += W[f][c] * X[c][ow]
// MFMA 32x32x16 bf16, A = w (m=f), B = x (n=ow)  ->  C/D col = lane&31 = ow.
// Block = 256 thr = 4 waves = (n, oh0..oh0+3); wave tile 64f x 64ow (2x2 MFMAs).
// All LDS fragment traffic is ds_read_b128 / ds_write_b128, 48 B strides
// (12-dword: 16B-aligned, 8-lane phases cover all 32 banks -> conflict-free).

#define N_  32
#define OH_ 62
#define OW_ 62

typedef __attribute__((ext_vector_type(8)))  short short8;
typedef __attribute__((ext_vector_type(16))) float float16;

__device__ __forceinline__ unsigned short f2bf(float v) {
    unsigned int u = __builtin_bit_cast(unsigned int, v);
    u += 0x7FFFu + ((u >> 16) & 1u);
    return (unsigned short)(u >> 16);
}
__device__ __forceinline__ unsigned int pack2(float a, float b) {
    return (unsigned int)f2bf(a) | ((unsigned int)f2bf(b) << 16);
}
__device__ __forceinline__ short8 bc(uint4 v) {
    return __builtin_bit_cast(short8, v);
}

// w [F][C][3][3] f32 -> wt bf16 [chunk4][tap9][half2][f64][j8]
// (so main-kernel staging is a straight uint4 copy, conflict-free on both ends)
__global__ __launch_bounds__(256) void wprep(const float* __restrict__ w,
                                             unsigned short* __restrict__ wt) {
    int tid  = blockIdx.x * 256 + threadIdx.x;   // 0..36863
    int j    = tid & 7;
    int f    = (tid >> 3) & 63;
    int half = (tid >> 9) & 1;
    int ct   = tid >> 10;                        // chunk*9 + tap
    int tap  = ct % 9;
    int chunk= ct / 9;
    wt[tid] = f2bf(w[(f * 64 + chunk * 16 + half * 8 + j) * 9 + tap]);
}

__global__ __launch_bounds__(256, 2) void conv_mfma(
    const float* __restrict__ x,
    const uint4* __restrict__ wt4,   // bf16, uint4 units of 8 values
    const float* __restrict__ b,
    float* __restrict__ out)
{
    // x: [row6][col66][half2] uint4 units, col-stride 3 u4 (48 B)
    __shared__ uint4 xl4[6 * 66 * 3];            // 19008 B
    // w: [tap9][f64][half2] uint4 units, f-stride 3 u4 (48 B)
    __shared__ uint4 wl4[9 * 64 * 3];            // 27648 B

    const int n    = blockIdx.x;
    const int oh0  = blockIdx.y * 4;
    const int t    = threadIdx.x;
    const int wv   = t >> 6;          // wave id = oh offset, wave-uniform
    const int ln31 = t & 31;
    const int cgrp = (t >> 5) & 1;    // k-half of the wave
    const int oh   = oh0 + wv;

    const float* xnb = x + (size_t)n * 64 * 4096;

    float16 acc00 = {0}, acc01 = {0}, acc10 = {0}, acc11 = {0};

    for (int chunk = 0; chunk < 4; ++chunk) {
        const int c0 = chunk * 16;
        __syncthreads();   // protect LDS from previous iteration's readers

        // ---- stage x: 6 rows x 64 cols x 16 c, f32 -> bf16, b128 writes ----
#pragma unroll
        for (int i = 0; i < 3; ++i) {
            int id   = t + 256 * i;          // 0..767
            int col  = id & 63;
            int rh   = id >> 6;              // 0..11
            int half = rh & 1;
            int row  = rh >> 1;              // 0..5
            int rowg = oh0 + row; if (rowg > 63) rowg = 63;
            const float* xp = xnb + (size_t)(c0 + half * 8) * 4096 + rowg * 64 + col;
            float v0 = xp[0];
            float v1 = xp[4096];
            float v2 = xp[2 * 4096];
            float v3 = xp[3 * 4096];
            float v4 = xp[4 * 4096];
            float v5 = xp[5 * 4096];
            float v6 = xp[6 * 4096];
            float v7 = xp[7 * 4096];
            uint4 pv = { pack2(v0, v1), pack2(v2, v3), pack2(v4, v5), pack2(v6, v7) };
            xl4[(row * 66 + col) * 3 + half] = pv;
        }

        // ---- stage w: straight uint4 copy into padded layout ----
        {
            const uint4* wc = wt4 + chunk * 1152;
#pragma unroll
            for (int i = 0; i < 5; ++i) {
                int id = t + 256 * i;        // 0..1279
                if (id < 1152) {
                    int f    = id & 63;
                    int half = (id >> 6) & 1;
                    int tap  = id >> 7;
                    wl4[(tap * 64 + f) * 3 + half] = wc[id];
                }
            }
        }
        __syncthreads();

        // ---- 9 taps x 2x2 MFMA, all frags via ds_read_b128 ----
#pragma unroll
        for (int r = 0; r < 3; ++r) {
            const int xrow = wv + r;
#pragma unroll
            for (int s = 0; s < 3; ++s) {
                const int tap = r * 3 + s;
                short8 a0 = bc(wl4[(tap * 64 + ln31)      * 3 + cgrp]);
                short8 a1 = bc(wl4[(tap * 64 + ln31 + 32) * 3 + cgrp]);
                short8 b0 = bc(xl4[(xrow * 66 + s + ln31)      * 3 + cgrp]);
                short8 b1 = bc(xl4[(xrow * 66 + s + ln31 + 32) * 3 + cgrp]);
                acc00 = __builtin_amdgcn_mfma_f32_32x32x16_bf16(a0, b0, acc00, 0, 0, 0);
                acc01 = __builtin_amdgcn_mfma_f32_32x32x16_bf16(a0, b1, acc01, 0, 0, 0);
                acc10 = __builtin_amdgcn_mfma_f32_32x32x16_bf16(a1, b0, acc10, 0, 0, 0);
                acc11 = __builtin_amdgcn_mfma_f32_32x32x16_bf16(a1, b1, acc11, 0, 0, 0);
            }
        }
    }

    // ---- epilogue: C/D row = (reg&3)+8*(reg>>2)+4*(lane>>5), col = lane&31 = ow ----
    if (oh < OH_) {
#pragma unroll
        for (int r = 0; r < 16; ++r) {
            int fr = (r & 3) + 8 * (r >> 2) + 4 * cgrp;
            float b0v = b[fr];
            float b1v = b[fr + 32];
            float* o0 = out + (((size_t)n * 64 + fr)      * OH_ + oh) * OW_;
            float* o1 = out + (((size_t)n * 64 + fr + 32) * OH_ + oh) * OW_;
            o0[ln31] = acc00[r] + b0v;
            o1[ln31] = acc10[r] + b1v;
            if (ln31 < 30) {
                o0[32 + ln31] = acc01[r] + b0v;
                o1[32 + ln31] = acc11[r] + b1v;
            }
        }
    }
}

extern "C" void kernel_launch(void* const* d_in, const int* in_sizes, int n_in,
                              void* d_out, int out_size, void* d_ws, size_t ws_size,
                              hipStream_t stream)
{
    const float* x = (const float*)d_in[0];
    const float* w = (const float*)d_in[1];
    const float* b = (const float*)d_in[2];
    float* out = (float*)d_out;
    unsigned short* wt = (unsigned short*)d_ws;   // 36864 bf16 = 73728 B

    wprep<<<144, 256, 0, stream>>>(w, wt);
    dim3 grid(N_, 16);                            // 32 images x 16 oh-blocks
    conv_mfma<<<grid, 256, 0, stream>>>(x, (const uint4*)wt, b, out);
}

// Round 4
// 93.387 us; speedup vs baseline: 6.5105x; 1.0237x over previous
//
#include <hip/hip_runtime.h>

// bf16 MFMA implicit GEMM for 3x3 valid conv + bias — pipelined-gather edition.
// x: [32,64,64,64] f32, w: [64,64,3,3] f32, b: [64] f32, out: [32,64,62,62] f32
//
// Per tap (r,s), per c-chunk of 16:  D[f][ow] += W[f][c] * X[c][ow]
// MFMA 32x32x16 bf16, A = w (m=f), B = x (n=ow)  ->  C/D col = lane&31 = ow.
// Block = 256 thr = 4 waves = (n, oh0..oh0+3); wave tile 64f x 64ow (2x2 MFMAs).
// Grid = 512 blocks = 2 blocks/CU (grid-limited), so the latency fix is
// in-wave pipelining: chunk k+1's global gathers are issued right after the
// second barrier and stay in flight across the whole 9-tap MFMA loop (which
// has no global ops -> no vmcnt waits until next chunk's pack).

#define N_  32
#define OH_ 62
#define OW_ 62

typedef __attribute__((ext_vector_type(8)))  short short8;
typedef __attribute__((ext_vector_type(16))) float float16;

__device__ __forceinline__ unsigned short f2bf(float v) {
    unsigned int u = __builtin_bit_cast(unsigned int, v);
    u += 0x7FFFu + ((u >> 16) & 1u);
    return (unsigned short)(u >> 16);
}
__device__ __forceinline__ unsigned int pack2(float a, float b) {
    return (unsigned int)f2bf(a) | ((unsigned int)f2bf(b) << 16);
}
__device__ __forceinline__ short8 bc(uint4 v) {
    return __builtin_bit_cast(short8, v);
}

// w [F][C][3][3] f32 -> wt bf16 [chunk4][tap9][half2][f64][j8]
__global__ __launch_bounds__(256) void wprep(const float* __restrict__ w,
                                             unsigned short* __restrict__ wt) {
    int tid  = blockIdx.x * 256 + threadIdx.x;   // 0..36863
    int j    = tid & 7;
    int f    = (tid >> 3) & 63;
    int half = (tid >> 9) & 1;
    int ct   = tid >> 10;                        // chunk*9 + tap
    int tap  = ct % 9;
    int chunk= ct / 9;
    wt[tid] = f2bf(w[(f * 64 + chunk * 16 + half * 8 + j) * 9 + tap]);
}

__global__ __launch_bounds__(256, 2) void conv_mfma(
    const float* __restrict__ x,
    const uint4* __restrict__ wt4,   // bf16, uint4 units of 8 values
    const float* __restrict__ b,
    float* __restrict__ out)
{
    // x: [row6][col66][half2] uint4 units, col-stride 3 u4 (48 B, conflict-free)
    __shared__ uint4 xl4[6 * 66 * 3];            // 19008 B
    // w: [tap9][f64][half2] uint4 units, f-stride 3 u4 (48 B)
    __shared__ uint4 wl4[9 * 64 * 3];            // 27648 B

    const int n    = blockIdx.x;
    const int oh0  = blockIdx.y * 4;
    const int t    = threadIdx.x;
    const int wv   = t >> 6;          // wave id = oh offset
    const int ln31 = t & 31;
    const int cgrp = (t >> 5) & 1;    // k-half of the wave
    const int oh   = oh0 + wv;

    const float* xnb = x + (size_t)n * 64 * 4096;

    float16 acc00 = {0}, acc01 = {0}, acc10 = {0}, acc11 = {0};

    // per-thread gather coordinates: 3 (row, c-half) slices, 64-lane col runs
    int colv[3], halfv[3], rowv[3], rowg[3];
#pragma unroll
    for (int i = 0; i < 3; ++i) {
        int id = t + 256 * i;         // 0..767
        colv[i]  = id & 63;
        int rh   = id >> 6;           // 0..11
        halfv[i] = rh & 1;
        rowv[i]  = rh >> 1;           // 0..5
        int rg = oh0 + rowv[i]; if (rg > 63) rg = 63;
        rowg[i] = rg;
    }

    float g[3][8];
    // ---- gather chunk 0 (exposed once) ----
#pragma unroll
    for (int i = 0; i < 3; ++i) {
        const float* xp = xnb + (size_t)(halfv[i] * 8) * 4096 + rowg[i] * 64 + colv[i];
#pragma unroll
        for (int j = 0; j < 8; ++j) g[i][j] = xp[(size_t)j * 4096];
    }

    for (int chunk = 0; chunk < 4; ++chunk) {
        __syncthreads();   // previous chunk's LDS readers done

        // ---- pack current gather regs -> LDS (b128 writes) ----
#pragma unroll
        for (int i = 0; i < 3; ++i) {
            uint4 pv = { pack2(g[i][0], g[i][1]), pack2(g[i][2], g[i][3]),
                         pack2(g[i][4], g[i][5]), pack2(g[i][6], g[i][7]) };
            xl4[(rowv[i] * 66 + colv[i]) * 3 + halfv[i]] = pv;
        }

        // ---- stage w chunk: straight uint4 copy (L2-resident after chunk 0) ----
        {
            const uint4* wc = wt4 + chunk * 1152;
#pragma unroll
            for (int i = 0; i < 5; ++i) {
                int id = t + 256 * i;        // 0..1279
                if (id < 1152) {
                    int f    = id & 63;
                    int half = (id >> 6) & 1;
                    int tap  = id >> 7;
                    wl4[(tap * 64 + f) * 3 + half] = wc[id];
                }
            }
        }
        __syncthreads();

        // ---- issue next chunk's gather NOW; it drains during the MFMA loop ----
        if (chunk < 3) {
            const int c0n = (chunk + 1) * 16;
#pragma unroll
            for (int i = 0; i < 3; ++i) {
                const float* xp = xnb + (size_t)(c0n + halfv[i] * 8) * 4096
                                      + rowg[i] * 64 + colv[i];
#pragma unroll
                for (int j = 0; j < 8; ++j) g[i][j] = xp[(size_t)j * 4096];
            }
        }

        // ---- 9 taps x 2x2 MFMA, frags via ds_read_b128 (no vmcnt ops here) ----
#pragma unroll
        for (int r = 0; r < 3; ++r) {
            const int xrow = wv + r;
#pragma unroll
            for (int s = 0; s < 3; ++s) {
                const int tap = r * 3 + s;
                short8 a0 = bc(wl4[(tap * 64 + ln31)      * 3 + cgrp]);
                short8 a1 = bc(wl4[(tap * 64 + ln31 + 32) * 3 + cgrp]);
                short8 b0 = bc(xl4[(xrow * 66 + s + ln31)      * 3 + cgrp]);
                short8 b1 = bc(xl4[(xrow * 66 + s + ln31 + 32) * 3 + cgrp]);
                acc00 = __builtin_amdgcn_mfma_f32_32x32x16_bf16(a0, b0, acc00, 0, 0, 0);
                acc01 = __builtin_amdgcn_mfma_f32_32x32x16_bf16(a0, b1, acc01, 0, 0, 0);
                acc10 = __builtin_amdgcn_mfma_f32_32x32x16_bf16(a1, b0, acc10, 0, 0, 0);
                acc11 = __builtin_amdgcn_mfma_f32_32x32x16_bf16(a1, b1, acc11, 0, 0, 0);
            }
        }
    }

    // ---- epilogue: C/D row = (reg&3)+8*(reg>>2)+4*(lane>>5), col = lane&31 = ow ----
    if (oh < OH_) {
#pragma unroll
        for (int r = 0; r < 16; ++r) {
            int fr = (r & 3) + 8 * (r >> 2) + 4 * cgrp;
            float b0v = b[fr];
            float b1v = b[fr + 32];
            float* o0 = out + (((size_t)n * 64 + fr)      * OH_ + oh) * OW_;
            float* o1 = out + (((size_t)n * 64 + fr + 32) * OH_ + oh) * OW_;
            o0[ln31] = acc00[r] + b0v;
            o1[ln31] = acc10[r] + b1v;
            if (ln31 < 30) {
                o0[32 + ln31] = acc01[r] + b0v;
                o1[32 + ln31] = acc11[r] + b1v;
            }
        }
    }
}

extern "C" void kernel_launch(void* const* d_in, const int* in_sizes, int n_in,
                              void* d_out, int out_size, void* d_ws, size_t ws_size,
                              hipStream_t stream)
{
    const float* x = (const float*)d_in[0];
    const float* w = (const float*)d_in[1];
    const float* b = (const float*)d_in[2];
    float* out = (float*)d_out;
    unsigned short* wt = (unsigned short*)d_ws;   // 36864 bf16 = 73728 B

    wprep<<<144, 256, 0, stream>>>(w, wt);
    dim3 grid(N_, 16);                            // 32 images x 16 oh-blocks
    conv_mfma<<<grid, 256, 0, stream>>>(x, (const uint4*)wt, b, out);
}